// Round 4
// baseline (122.855 us; speedup 1.0000x reference)
//
#include <hip/hip_runtime.h>

// Problem constants (from reference)
#define V 49688
#define D 128
#define B 16
#define N 100
#define VD (V * D)        // 6,360,064 floats per batch
#define VD4 (VD / 4)      // 1,590,016 float4 per batch (= 256 * 6211; 6211 prime)

typedef float f32x4 __attribute__((ext_vector_type(4)));

// Kernel 1 (R4 discriminator): fillBuffer-mimic.
// grid (1553, 16), block 256. Each block owns a 1024-float4 contiguous chunk of
// one batch; each thread handles 4 float4 at stride 256. Plain stores (L2
// write-allocate, like the harness fill kernel that hits 7.0 TB/s), per-batch
// contiguous dispatch (blockIdx.x fastest -> chip-wide single rolling write
// stream), ILP=4. W re-read per batch comes from L3 (25 MB resident).
__global__ __launch_bounds__(256) void GlobalGatedUpdate_copy_kernel(
    const f32x4* __restrict__ W4, f32x4* __restrict__ out4) {
  int c = blockIdx.x * 1024 + threadIdx.x;           // base f4 index in W
  f32x4* dst = out4 + (size_t)blockIdx.y * VD4;
  f32x4 v0, v1, v2, v3;
  bool g0 = (c + 0 * 256) < VD4;
  bool g1 = (c + 1 * 256) < VD4;
  bool g2 = (c + 2 * 256) < VD4;
  bool g3 = (c + 3 * 256) < VD4;
  if (g0) v0 = W4[c + 0 * 256];
  if (g1) v1 = W4[c + 1 * 256];
  if (g2) v2 = W4[c + 2 * 256];
  if (g3) v3 = W4[c + 3 * 256];
  if (g0) dst[c + 0 * 256] = v0;
  if (g1) dst[c + 1 * 256] = v1;
  if (g2) dst[c + 2 * 256] = v2;
  if (g3) dst[c + 3 * 256] = v3;
}

// Kernel 2: for each (b, i): v = nodes[b*N+i];
//   out[b][v][:] = (1 - alpha[v]) * W[v][:] + alpha[v] * x[i][:]
__global__ __launch_bounds__(256) void GlobalGatedUpdate_scatter_kernel(
    const int* __restrict__ nodes, const float* __restrict__ x,
    const float* __restrict__ W, const float* __restrict__ alpha,
    float* __restrict__ out) {
  int t = blockIdx.x * 256 + threadIdx.x;            // 0 .. B*N*32 - 1
  int d4  = t & 31;                                  // float4 index within row
  int row = t >> 5;                                  // 0 .. 1599 (= b*N + i)
  int b = row / N;
  int i = row - b * N;                               // position in node list -> x row
  int v = nodes[row];
  float a = alpha[v];                                // alpha is (V,1)
  f32x4 wv = ((const f32x4*)W)[v * 32 + d4];
  f32x4 xv = ((const f32x4*)x)[i * 32 + d4];
  f32x4 res = (1.0f - a) * wv + a * xv;
  ((f32x4*)out)[(size_t)b * (size_t)VD4 + (size_t)(v * 32 + d4)] = res;
}

extern "C" void kernel_launch(void* const* d_in, const int* in_sizes, int n_in,
                              void* d_out, int out_size, void* d_ws, size_t ws_size,
                              hipStream_t stream) {
  const int*   nodes = (const int*)d_in[0];   // (B, N) int32
  const float* x     = (const float*)d_in[1]; // (B*N, D) f32
  const float* W     = (const float*)d_in[2]; // (V, D) f32
  const float* alpha = (const float*)d_in[3]; // (V, 1) f32
  float* out = (float*)d_out;                 // (B, V, D) f32

  dim3 grid_copy((VD4 + 1023) / 1024, B);     // 1553 x 16
  GlobalGatedUpdate_copy_kernel<<<grid_copy, 256, 0, stream>>>(
      (const f32x4*)W, (f32x4*)out);

  GlobalGatedUpdate_scatter_kernel<<<(B * N * 32) / 256, 256, 0, stream>>>(
      nodes, x, W, alpha, out);
}

// Round 5
// 79.913 us; speedup vs baseline: 1.5374x; 1.5374x over previous
//
#include <hip/hip_runtime.h>

// Problem constants (from reference)
#define V 49688
#define D 128
#define B 16
#define N 100
#define VD (V * D)        // 6,360,064 floats per batch
#define VD4 (VD / 4)      // 1,590,016 float4 per batch (= 256 * 6211; 6211 prime)

typedef float f32x4 __attribute__((ext_vector_type(4)));

// Kernel 1 (R5): NT broadcast with ILP=4.
// Ladder: R2 NT-broadcast=88us (best), plain variants 94-123us. Keep NT +
// read-once; attack the remaining 5.2 vs 7.0 TB/s gap via MLP/burst size:
// each thread loads 4 float4 (independent, all in flight), then stores
// batch-major -> 4 consecutive 1KB wave-stores per batch region (4KB bursts),
// 64 NT stores/thread. grid 1553 blocks (last one guarded).
__global__ __launch_bounds__(256) void GlobalGatedUpdate_copy_kernel(
    const f32x4* __restrict__ W4, f32x4* __restrict__ out4) {
  int c = blockIdx.x * 1024 + threadIdx.x;   // base f4 index of this thread
  f32x4 v0, v1, v2, v3;
  bool g0 = (c + 0 * 256) < VD4;
  bool g1 = (c + 1 * 256) < VD4;
  bool g2 = (c + 2 * 256) < VD4;
  bool g3 = (c + 3 * 256) < VD4;
  if (g0) v0 = W4[c + 0 * 256];
  if (g1) v1 = W4[c + 1 * 256];
  if (g2) v2 = W4[c + 2 * 256];
  if (g3) v3 = W4[c + 3 * 256];
  #pragma unroll
  for (int b = 0; b < B; ++b) {
    f32x4* dst = out4 + (size_t)b * VD4 + c;
    if (g0) __builtin_nontemporal_store(v0, dst + 0 * 256);
    if (g1) __builtin_nontemporal_store(v1, dst + 1 * 256);
    if (g2) __builtin_nontemporal_store(v2, dst + 2 * 256);
    if (g3) __builtin_nontemporal_store(v3, dst + 3 * 256);
  }
}

// Kernel 2: for each (b, i): v = nodes[b*N+i];
//   out[b][v][:] = (1 - alpha[v]) * W[v][:] + alpha[v] * x[i][:]
__global__ __launch_bounds__(256) void GlobalGatedUpdate_scatter_kernel(
    const int* __restrict__ nodes, const float* __restrict__ x,
    const float* __restrict__ W, const float* __restrict__ alpha,
    float* __restrict__ out) {
  int t = blockIdx.x * 256 + threadIdx.x;            // 0 .. B*N*32 - 1
  int d4  = t & 31;                                  // float4 index within row
  int row = t >> 5;                                  // 0 .. 1599 (= b*N + i)
  int b = row / N;
  int i = row - b * N;                               // position in node list -> x row
  int v = nodes[row];
  float a = alpha[v];                                // alpha is (V,1)
  f32x4 wv = ((const f32x4*)W)[v * 32 + d4];
  f32x4 xv = ((const f32x4*)x)[i * 32 + d4];
  f32x4 res = (1.0f - a) * wv + a * xv;
  ((f32x4*)out)[(size_t)b * (size_t)VD4 + (size_t)(v * 32 + d4)] = res;
}

extern "C" void kernel_launch(void* const* d_in, const int* in_sizes, int n_in,
                              void* d_out, int out_size, void* d_ws, size_t ws_size,
                              hipStream_t stream) {
  const int*   nodes = (const int*)d_in[0];   // (B, N) int32
  const float* x     = (const float*)d_in[1]; // (B*N, D) f32
  const float* W     = (const float*)d_in[2]; // (V, D) f32
  const float* alpha = (const float*)d_in[3]; // (V, 1) f32
  float* out = (float*)d_out;                 // (B, V, D) f32

  GlobalGatedUpdate_copy_kernel<<<(VD4 + 1023) / 1024, 256, 0, stream>>>(
      (const f32x4*)W, (f32x4*)out);

  GlobalGatedUpdate_scatter_kernel<<<(B * N * 32) / 256, 256, 0, stream>>>(
      nodes, x, W, alpha, out);
}